// Round 1
// baseline (749.069 us; speedup 1.0000x reference)
//
#include <hip/hip_runtime.h>

// H2GCN fused pipeline, fp32 correctness-first version.
// Pipeline: deg -> dis -> CSR(rowptr,col,w) -> spmm x->agg1 -> spmm agg1->agg2
//           -> fused [relu(in_k@Wk+bk)]@Wc_k accumulation -> out

#define FD 256   // D == H == 256
#define CO 64    // out channels

__global__ void init_kernel(int* deg, int* fill, int n) {
    int i = blockIdx.x * blockDim.x + threadIdx.x;
    if (i < n) { deg[i] = 1; fill[i] = 0; }   // self-loop contributes 1
}

__global__ void count_kernel(const int* __restrict__ ei0, int* deg, int e) {
    int i = blockIdx.x * blockDim.x + threadIdx.x;
    if (i < e) atomicAdd(&deg[ei0[i]], 1);
}

__global__ void dis_kernel(const int* __restrict__ deg, float* __restrict__ dis, int n) {
    int i = blockIdx.x * blockDim.x + threadIdx.x;
    if (i < n) dis[i] = rsqrtf((float)deg[i]);   // deg >= 1 always (self loop)
}

// single-block exclusive scan over deg -> rowptr[0..n], rowptr[n] = total
__global__ void scan_kernel(const int* __restrict__ deg, int* __restrict__ rowptr, int n) {
    __shared__ int part[1024];
    const int tid = threadIdx.x;
    const int CH = (n + 1023) / 1024;
    const int base = tid * CH;
    int s = 0;
    for (int i = 0; i < CH; ++i) {
        int idx = base + i;
        if (idx < n) s += deg[idx];
    }
    part[tid] = s;
    __syncthreads();
    for (int off = 1; off < 1024; off <<= 1) {
        int v = part[tid];
        int add = (tid >= off) ? part[tid - off] : 0;
        __syncthreads();
        part[tid] = v + add;
        __syncthreads();
    }
    int run = (tid == 0) ? 0 : part[tid - 1];
    for (int i = 0; i < CH; ++i) {
        int idx = base + i;
        if (idx < n) { rowptr[idx] = run; run += deg[idx]; }
    }
    if (tid == 0) rowptr[n] = part[1023];
}

__global__ void fill_kernel(const int* __restrict__ ei, const float* __restrict__ dis,
                            const int* __restrict__ rowptr, int* fill,
                            int* __restrict__ col, float* __restrict__ wv, int e, int n) {
    int i = blockIdx.x * blockDim.x + threadIdx.x;
    if (i >= e + n) return;
    int r, c;
    if (i < e) { r = ei[i]; c = ei[e + i]; }
    else       { r = i - e; c = r; }           // self loops appended
    float w = dis[r] * dis[c];
    int pos = rowptr[r] + atomicAdd(&fill[r], 1);
    col[pos] = c;
    wv[pos]  = w;
}

// one wave per row; lane covers 4 of 256 cols; no atomics
__global__ void spmm_kernel(const int* __restrict__ rowptr, const int* __restrict__ col,
                            const float* __restrict__ wv, const float* __restrict__ x,
                            float* __restrict__ out, int n) {
    int row = blockIdx.x * 4 + (threadIdx.x >> 6);
    if (row >= n) return;
    int lane = threadIdx.x & 63;
    int p0 = rowptr[row], p1 = rowptr[row + 1];
    float ax = 0.f, ay = 0.f, az = 0.f, aw = 0.f;
    for (int p = p0; p < p1; ++p) {
        int c  = col[p];
        float w = wv[p];
        float4 v = *(const float4*)(x + (size_t)c * FD + lane * 4);
        ax += w * v.x; ay += w * v.y; az += w * v.z; aw += w * v.w;
    }
    float4 o; o.x = ax; o.y = ay; o.z = az; o.w = aw;
    *(float4*)(out + (size_t)row * FD + lane * 4) = o;
}

// fused: out[r][c] = bc[c] + sum_k relu(in_k @ Wk + bk)[r][:] @ Wc_k[:][c]
// 32 rows per block, 256 threads.
__launch_bounds__(256, 2)
__global__ void fused_gemm(const float* __restrict__ x, const float* __restrict__ agg1,
                           const float* __restrict__ agg2,
                           const float* __restrict__ W0, const float* __restrict__ b0,
                           const float* __restrict__ W1, const float* __restrict__ b1,
                           const float* __restrict__ W2, const float* __restrict__ b2,
                           const float* __restrict__ Wc, const float* __restrict__ bc,
                           float* __restrict__ out, int n) {
    // region A (36 KB): lin[32][32] (4 KB) + lwk[32][256] (32 KB); aliased by lwc[64][64] (16 KB) in stage C
    __shared__ __align__(16) float smemA[9216];
    __shared__ __align__(16) float lt[32][256];      // 32 KB
    float (*lin)[32]  = (float(*)[32])smemA;
    float (*lwk)[256] = (float(*)[256])(smemA + 1024);
    float (*lwc)[64]  = (float(*)[64])smemA;

    const int tid  = threadIdx.x;
    const int row0 = blockIdx.x * 32;

    // stage B mapping: wave-uniform row group (8 rows), lane covers 4 t-cols
    const int rgB = tid >> 6;            // 0..3
    const int j0  = (tid & 63) * 4;      // 0..252

    // stage C mapping: 4 rows x 2 out-cols per thread
    const int rgC = tid >> 5;            // 0..7
    const int c0  = (tid & 31) * 2;      // 0..62

    float oacc[4][2];
    #pragma unroll
    for (int i = 0; i < 4; ++i) { oacc[i][0] = bc[c0]; oacc[i][1] = bc[c0 + 1]; }

    for (int k = 0; k < 3; ++k) {
        const float* inp = (k == 0) ? x  : (k == 1) ? agg1 : agg2;
        const float* Wk  = (k == 0) ? W0 : (k == 1) ? W1   : W2;
        const float* bk  = (k == 0) ? b0 : (k == 1) ? b1   : b2;

        float4 acc[8];
        float4 bk4 = *(const float4*)(bk + j0);
        #pragma unroll
        for (int i = 0; i < 8; ++i) acc[i] = bk4;   // bias pre-loaded

        for (int dt = 0; dt < 8; ++dt) {
            __syncthreads();   // protect lin/lwk (and region-A lwc from prev k)
            {   // load lin[32][32] <- in rows, d-slice
                int r  = tid >> 3;
                int dl = (tid & 7) * 4;
                int gr = row0 + r;
                float4 v;
                if (gr < n) v = *(const float4*)(inp + (size_t)gr * FD + dt * 32 + dl);
                else        v = make_float4(0.f, 0.f, 0.f, 0.f);
                *(float4*)&lin[r][dl] = v;
            }
            {   // load lwk[32][256] <- Wk d-slice (contiguous 32 KB)
                const float4* src = (const float4*)(Wk + (size_t)dt * 32 * FD);
                float4* dst = (float4*)lwk;
                #pragma unroll
                for (int it = 0; it < 8; ++it) dst[it * 256 + tid] = src[it * 256 + tid];
            }
            __syncthreads();
            #pragma unroll
            for (int dc = 0; dc < 8; ++dc) {
                float4 bq0 = *(const float4*)&lwk[dc * 4 + 0][j0];
                float4 bq1 = *(const float4*)&lwk[dc * 4 + 1][j0];
                float4 bq2 = *(const float4*)&lwk[dc * 4 + 2][j0];
                float4 bq3 = *(const float4*)&lwk[dc * 4 + 3][j0];
                #pragma unroll
                for (int i = 0; i < 8; ++i) {
                    float4 a = *(const float4*)&lin[rgB * 8 + i][dc * 4];   // wave-uniform
                    acc[i].x += a.x * bq0.x + a.y * bq1.x + a.z * bq2.x + a.w * bq3.x;
                    acc[i].y += a.x * bq0.y + a.y * bq1.y + a.z * bq2.y + a.w * bq3.y;
                    acc[i].z += a.x * bq0.z + a.y * bq1.z + a.z * bq2.z + a.w * bq3.z;
                    acc[i].w += a.x * bq0.w + a.y * bq1.w + a.z * bq2.w + a.w * bq3.w;
                }
            }
        }
        // t -> LDS with relu (bias already in acc)
        #pragma unroll
        for (int i = 0; i < 8; ++i) {
            float4 v = acc[i];
            v.x = fmaxf(v.x, 0.f); v.y = fmaxf(v.y, 0.f);
            v.z = fmaxf(v.z, 0.f); v.w = fmaxf(v.w, 0.f);
            *(float4*)&lt[rgB * 8 + i][j0] = v;
        }
        __syncthreads();

        // stage C: out += relu(t) @ Wc_k
        for (int jt2 = 0; jt2 < 4; ++jt2) {
            if (jt2) __syncthreads();
            {   // load lwc[64][64] <- Wc_k j-slice (contiguous 16 KB)
                const float4* src = (const float4*)(Wc + ((size_t)k * 256 + jt2 * 64) * CO);
                float4* dst = (float4*)lwc;
                #pragma unroll
                for (int it = 0; it < 4; ++it) dst[it * 256 + tid] = src[it * 256 + tid];
            }
            __syncthreads();
            #pragma unroll
            for (int jc = 0; jc < 16; ++jc) {
                int jl = jc * 4;
                float2 w0 = *(const float2*)&lwc[jl + 0][c0];
                float2 w1 = *(const float2*)&lwc[jl + 1][c0];
                float2 w2 = *(const float2*)&lwc[jl + 2][c0];
                float2 w3 = *(const float2*)&lwc[jl + 3][c0];
                #pragma unroll
                for (int i = 0; i < 4; ++i) {
                    float4 a = *(const float4*)&lt[rgC * 4 + i][jt2 * 64 + jl];  // wave-uniform-ish
                    oacc[i][0] += a.x * w0.x + a.y * w1.x + a.z * w2.x + a.w * w3.x;
                    oacc[i][1] += a.x * w0.y + a.y * w1.y + a.z * w2.y + a.w * w3.y;
                }
            }
        }
        // next k's first barrier protects lt / region A reuse
    }

    #pragma unroll
    for (int i = 0; i < 4; ++i) {
        int gr = row0 + rgC * 4 + i;
        if (gr < n) {
            out[(size_t)gr * CO + c0]     = oacc[i][0];
            out[(size_t)gr * CO + c0 + 1] = oacc[i][1];
        }
    }
}

extern "C" void kernel_launch(void* const* d_in, const int* in_sizes, int n_in,
                              void* d_out, int out_size, void* d_ws, size_t ws_size,
                              hipStream_t stream) {
    const float* x  = (const float*)d_in[0];
    const int*   ei = (const int*)d_in[1];
    // d_in[2] = num_nodes (scalar), unused; sizes derived below
    const float* W0 = (const float*)d_in[3];
    const float* b0 = (const float*)d_in[4];
    const float* W1 = (const float*)d_in[5];
    const float* b1 = (const float*)d_in[6];
    const float* W2 = (const float*)d_in[7];
    const float* b2 = (const float*)d_in[8];
    const float* Wc = (const float*)d_in[9];
    const float* bc = (const float*)d_in[10];
    float* out = (float*)d_out;

    const int n  = in_sizes[0] / FD;   // 50000
    const int e  = in_sizes[1] / 2;    // 400000
    const int ep = e + n;              // edges incl. self loops

    char* ws = (char*)d_ws;
    size_t o = 0;
    auto take = [&](size_t nbytes) -> char* {
        char* p = ws + o;
        o += (nbytes + 255) & ~(size_t)255;
        return p;
    };
    int*   deg    = (int*)  take((size_t)n * 4);
    int*   fill   = (int*)  take((size_t)n * 4);
    float* dis    = (float*)take((size_t)n * 4);
    int*   rowptr = (int*)  take((size_t)(n + 1) * 4);
    int*   col    = (int*)  take((size_t)ep * 4);
    float* wv     = (float*)take((size_t)ep * 4);
    float* agg1   = (float*)take((size_t)n * FD * 4);
    float* agg2   = (float*)take((size_t)n * FD * 4);
    (void)ws_size; (void)n_in; (void)out_size;

    init_kernel <<<(n + 255) / 256, 256, 0, stream>>>(deg, fill, n);
    count_kernel<<<(e + 255) / 256, 256, 0, stream>>>(ei, deg, e);
    dis_kernel  <<<(n + 255) / 256, 256, 0, stream>>>(deg, dis, n);
    scan_kernel <<<1, 1024, 0, stream>>>(deg, rowptr, n);
    fill_kernel <<<(ep + 255) / 256, 256, 0, stream>>>(ei, dis, rowptr, fill, col, wv, e, n);
    spmm_kernel <<<(n + 3) / 4, 256, 0, stream>>>(rowptr, col, wv, x, agg1, n);
    spmm_kernel <<<(n + 3) / 4, 256, 0, stream>>>(rowptr, col, wv, agg1, agg2, n);
    fused_gemm  <<<(n + 31) / 32, 256, 0, stream>>>(x, agg1, agg2,
                                                    W0, b0, W1, b1, W2, b2,
                                                    Wc, bc, out, n);
}

// Round 2
// 382.356 us; speedup vs baseline: 1.9591x; 1.9591x over previous
//
#include <hip/hip_runtime.h>

// H2GCN: CSR build (fp32) -> bf16 SpMM x2 -> fused MFMA GEMM (bf16 in, fp32 acc)
// t^T-orientation trick: stage B computes t^T = WkT @ in^T so the MFMA D-frag's
// reg-contiguous dim (M) is the t-col dim -> ds_write_b64 packing into row-major
// t LDS; stage C computes out^T = WcT @ t^T reading t with the same K-contiguous
// fragment pattern.

#define FD 256   // D == H == 256
#define CO 64    // out channels
#define LDSROW 264  // padded LDS row, bf16 elems (528 B = 2-way-conflict pattern)

using frag_ab = __attribute__((ext_vector_type(8))) short;  // 8 bf16
using f32x4   = __attribute__((ext_vector_type(4))) float;

__device__ inline unsigned short f2bf(float f) {
    unsigned int u = __builtin_bit_cast(unsigned int, f);
    unsigned int r = (u + 0x7FFFu + ((u >> 16) & 1u)) >> 16;
    return (unsigned short)r;
}
__device__ inline float bf2f(unsigned short u) {
    unsigned int v = ((unsigned int)u) << 16;
    return __builtin_bit_cast(float, v);
}

__global__ void init_kernel(int* deg, int* fill, int n) {
    int i = blockIdx.x * blockDim.x + threadIdx.x;
    if (i < n) { deg[i] = 1; fill[i] = 0; }   // self-loop contributes 1
}

__global__ void count_kernel(const int* __restrict__ ei0, int* deg, int e) {
    int i = blockIdx.x * blockDim.x + threadIdx.x;
    if (i < e) atomicAdd(&deg[ei0[i]], 1);
}

__global__ void dis_kernel(const int* __restrict__ deg, float* __restrict__ dis, int n) {
    int i = blockIdx.x * blockDim.x + threadIdx.x;
    if (i < n) dis[i] = rsqrtf((float)deg[i]);
}

__global__ void scan_kernel(const int* __restrict__ deg, int* __restrict__ rowptr, int n) {
    __shared__ int part[1024];
    const int tid = threadIdx.x;
    const int CH = (n + 1023) / 1024;
    const int base = tid * CH;
    int s = 0;
    for (int i = 0; i < CH; ++i) {
        int idx = base + i;
        if (idx < n) s += deg[idx];
    }
    part[tid] = s;
    __syncthreads();
    for (int off = 1; off < 1024; off <<= 1) {
        int v = part[tid];
        int add = (tid >= off) ? part[tid - off] : 0;
        __syncthreads();
        part[tid] = v + add;
        __syncthreads();
    }
    int run = (tid == 0) ? 0 : part[tid - 1];
    for (int i = 0; i < CH; ++i) {
        int idx = base + i;
        if (idx < n) { rowptr[idx] = run; run += deg[idx]; }
    }
    if (tid == 0) rowptr[n] = part[1023];
}

__global__ void fill_kernel(const int* __restrict__ ei, const float* __restrict__ dis,
                            const int* __restrict__ rowptr, int* fill,
                            int* __restrict__ col, float* __restrict__ wv, int e, int n) {
    int i = blockIdx.x * blockDim.x + threadIdx.x;
    if (i >= e + n) return;
    int r, c;
    if (i < e) { r = ei[i]; c = ei[e + i]; }
    else       { r = i - e; c = r; }
    float w = dis[r] * dis[c];
    int pos = rowptr[r] + atomicAdd(&fill[r], 1);
    col[pos] = c;
    wv[pos]  = w;
}

// fp32 -> bf16 convert, 4 elems/thread
__global__ void conv_kernel(const float* __restrict__ x, unsigned short* __restrict__ xb, int total4) {
    int i = blockIdx.x * blockDim.x + threadIdx.x;
    if (i < total4) {
        float4 v = ((const float4*)x)[i];
        ushort4 o;
        o.x = f2bf(v.x); o.y = f2bf(v.y); o.z = f2bf(v.z); o.w = f2bf(v.w);
        ((ushort4*)xb)[i] = o;
    }
}

// transpose+convert weights: W0/W1/W2 [256][256] -> WkT bf16 [3][256][256] (out-major),
// Wc [768][64] -> WcT bf16 [64][768]
__global__ void wtrans_kernel(const float* __restrict__ W0, const float* __restrict__ W1,
                              const float* __restrict__ W2, const float* __restrict__ Wc,
                              unsigned short* __restrict__ WkT, unsigned short* __restrict__ WcT) {
    __shared__ unsigned short tl[64][65];
    int b = blockIdx.x;
    const float* src; unsigned short* dst; int R, C, r0, c0;
    if (b < 48) {
        int k = b >> 4, t = b & 15;
        src = (k == 0) ? W0 : (k == 1) ? W1 : W2;
        dst = WkT + k * 65536;
        R = 256; C = 256; r0 = (t >> 2) * 64; c0 = (t & 3) * 64;
    } else {
        int t = b - 48;
        src = Wc; dst = WcT;
        R = 768; C = 64; r0 = t * 64; c0 = 0;
    }
    int tid = threadIdx.x;
    int rr = tid >> 4, cc = (tid & 15) * 4;
    #pragma unroll
    for (int it = 0; it < 4; ++it) {
        int r = it * 16 + rr;
        float4 v = *(const float4*)(src + (size_t)(r0 + r) * C + c0 + cc);
        tl[cc + 0][r] = f2bf(v.x); tl[cc + 1][r] = f2bf(v.y);
        tl[cc + 2][r] = f2bf(v.z); tl[cc + 3][r] = f2bf(v.w);
    }
    __syncthreads();
    #pragma unroll
    for (int it = 0; it < 4; ++it) {
        int crow = it * 16 + rr;           // dst row (src col)
        ushort4 o;
        o.x = tl[crow][cc + 0]; o.y = tl[crow][cc + 1];
        o.z = tl[crow][cc + 2]; o.w = tl[crow][cc + 3];
        *(ushort4*)(dst + (size_t)(c0 + crow) * R + r0 + cc) = o;
    }
}

// one row per wave, bf16 gathers, fp32 accum, bf16 out
__global__ void spmm_bf16(const int* __restrict__ rowptr, const int* __restrict__ col,
                          const float* __restrict__ wv, const unsigned short* __restrict__ xb,
                          unsigned short* __restrict__ outb, int n) {
    int row = blockIdx.x * 4 + (threadIdx.x >> 6);
    if (row >= n) return;
    int lane = threadIdx.x & 63;
    int p0 = rowptr[row], p1 = rowptr[row + 1];
    float a0 = 0.f, a1 = 0.f, a2 = 0.f, a3 = 0.f;
    for (int p = p0; p < p1; ++p) {
        int c = col[p];
        float wt = wv[p];
        ushort4 v = *(const ushort4*)(xb + (size_t)c * FD + lane * 4);
        a0 += wt * bf2f(v.x); a1 += wt * bf2f(v.y);
        a2 += wt * bf2f(v.z); a3 += wt * bf2f(v.w);
    }
    ushort4 o;
    o.x = f2bf(a0); o.y = f2bf(a1); o.z = f2bf(a2); o.w = f2bf(a3);
    *(ushort4*)(outb + (size_t)row * FD + lane * 4) = o;
}

// fused MFMA: per 64-row block, for k=0..2: t^T = relu(WkT @ in^T + bk),
// out^T += WcT_k @ t^T ; finally out += bc.
__launch_bounds__(256, 3)
__global__ void fused_mfma(const unsigned short* __restrict__ xb,
                           const unsigned short* __restrict__ agg1b,
                           const unsigned short* __restrict__ agg2b,
                           const unsigned short* __restrict__ WkT,
                           const float* __restrict__ b0, const float* __restrict__ b1,
                           const float* __restrict__ b2,
                           const unsigned short* __restrict__ WcT,
                           const float* __restrict__ bc,
                           float* __restrict__ out, int n) {
    __shared__ unsigned short lds[64 * LDSROW];   // 33792 B, reused in-tile / t-tile
    const int tid = threadIdx.x;
    const int w = tid >> 6;            // wave 0..3
    const int l = tid & 63;
    const int l4 = l >> 4, lm = l & 15;
    const int row0 = blockIdx.x * 64;

    f32x4 oacc[4];
    #pragma unroll
    for (int am = 0; am < 4; ++am) oacc[am] = (f32x4)(0.f);

    for (int k = 0; k < 3; ++k) {
        const unsigned short* inb = (k == 0) ? xb : (k == 1) ? agg1b : agg2b;
        const unsigned short* WT  = WkT + k * 65536;
        const float* bk = (k == 0) ? b0 : (k == 1) ? b1 : b2;

        __syncthreads();   // protect lds (t of prev hop done being read)
        {   // stage in-tile: 64 rows x 256 bf16, thread -> row tid>>2, 64-elem seg
            int r = tid >> 2, c0 = (tid & 3) * 64;
            int gr = row0 + r;
            unsigned short* dst = lds + r * LDSROW + c0;
            if (gr < n) {
                const unsigned short* src = inb + (size_t)gr * FD + c0;
                #pragma unroll
                for (int u = 0; u < 8; ++u)
                    *(uint4*)(dst + u * 8) = *(const uint4*)(src + u * 8);
            } else {
                #pragma unroll
                for (int u = 0; u < 8; ++u)
                    *(uint4*)(dst + u * 8) = make_uint4(0, 0, 0, 0);
            }
        }
        __syncthreads();

        // stage B: t^T[j][r], wave w owns j in [w*64, w*64+64)
        f32x4 acc[4][4];
        #pragma unroll
        for (int jm = 0; jm < 4; ++jm)
            #pragma unroll
            for (int rn = 0; rn < 4; ++rn) acc[jm][rn] = (f32x4)(0.f);

        for (int kk = 0; kk < 8; ++kk) {
            const int k0 = kk * 32;
            frag_ab a[4], bfr[4];
            #pragma unroll
            for (int jm = 0; jm < 4; ++jm)
                a[jm] = *(const frag_ab*)(WT + (size_t)(w * 64 + jm * 16 + lm) * 256 + k0 + 8 * l4);
            #pragma unroll
            for (int rn = 0; rn < 4; ++rn)
                bfr[rn] = *(const frag_ab*)(lds + (rn * 16 + lm) * LDSROW + k0 + 8 * l4);
            #pragma unroll
            for (int jm = 0; jm < 4; ++jm)
                #pragma unroll
                for (int rn = 0; rn < 4; ++rn)
                    acc[jm][rn] = __builtin_amdgcn_mfma_f32_16x16x32_bf16(a[jm], bfr[rn], acc[jm][rn], 0, 0, 0);
        }
        __syncthreads();   // done reading in-tile

        // bias + relu + pack -> t row-major [64][LDSROW] (row r, col j)
        #pragma unroll
        for (int jm = 0; jm < 4; ++jm) {
            float4 bb = *(const float4*)(bk + w * 64 + jm * 16 + l4 * 4);
            #pragma unroll
            for (int rn = 0; rn < 4; ++rn) {
                f32x4 v = acc[jm][rn];
                ushort4 p;
                p.x = f2bf(fmaxf(v[0] + bb.x, 0.f));
                p.y = f2bf(fmaxf(v[1] + bb.y, 0.f));
                p.z = f2bf(fmaxf(v[2] + bb.z, 0.f));
                p.w = f2bf(fmaxf(v[3] + bb.w, 0.f));
                *(ushort4*)(lds + (rn * 16 + lm) * LDSROW + w * 64 + jm * 16 + l4 * 4) = p;
            }
        }
        __syncthreads();

        // stage C: out^T += WcT_k @ t^T ; wave w owns rows r = w*16+lm
        for (int kk = 0; kk < 8; ++kk) {
            const int k0 = kk * 32;
            frag_ab bfr = *(const frag_ab*)(lds + (w * 16 + lm) * LDSROW + k0 + 8 * l4);
            #pragma unroll
            for (int am = 0; am < 4; ++am) {
                frag_ab afr = *(const frag_ab*)(WcT + (size_t)(am * 16 + lm) * 768 + k * 256 + k0 + 8 * l4);
                oacc[am] = __builtin_amdgcn_mfma_f32_16x16x32_bf16(afr, bfr, oacc[am], 0, 0, 0);
            }
        }
    }

    // out^T[c][r] -> out[r][c], add bc
    int gr = row0 + w * 16 + lm;
    if (gr < n) {
        #pragma unroll
        for (int am = 0; am < 4; ++am) {
            float4 bb = *(const float4*)(bc + am * 16 + l4 * 4);
            float4 o;
            o.x = oacc[am][0] + bb.x;
            o.y = oacc[am][1] + bb.y;
            o.z = oacc[am][2] + bb.z;
            o.w = oacc[am][3] + bb.w;
            *(float4*)(out + (size_t)gr * CO + am * 16 + l4 * 4) = o;
        }
    }
}

extern "C" void kernel_launch(void* const* d_in, const int* in_sizes, int n_in,
                              void* d_out, int out_size, void* d_ws, size_t ws_size,
                              hipStream_t stream) {
    const float* x  = (const float*)d_in[0];
    const int*   ei = (const int*)d_in[1];
    const float* W0 = (const float*)d_in[3];
    const float* b0 = (const float*)d_in[4];
    const float* W1 = (const float*)d_in[5];
    const float* b1 = (const float*)d_in[6];
    const float* W2 = (const float*)d_in[7];
    const float* b2 = (const float*)d_in[8];
    const float* Wc = (const float*)d_in[9];
    const float* bc = (const float*)d_in[10];
    float* out = (float*)d_out;

    const int n  = in_sizes[0] / FD;   // 50000
    const int e  = in_sizes[1] / 2;    // 400000
    const int ep = e + n;

    char* ws = (char*)d_ws;
    size_t o = 0;
    auto take = [&](size_t nbytes) -> char* {
        char* p = ws + o;
        o += (nbytes + 255) & ~(size_t)255;
        return p;
    };
    int*   deg    = (int*)  take((size_t)n * 4);
    int*   fill   = (int*)  take((size_t)n * 4);
    float* dis    = (float*)take((size_t)n * 4);
    int*   rowptr = (int*)  take((size_t)(n + 1) * 4);
    int*   col    = (int*)  take((size_t)ep * 4);
    float* wv     = (float*)take((size_t)ep * 4);
    unsigned short* xb    = (unsigned short*)take((size_t)n * FD * 2);
    unsigned short* agg1b = (unsigned short*)take((size_t)n * FD * 2);
    unsigned short* agg2b = (unsigned short*)take((size_t)n * FD * 2);
    unsigned short* WkT   = (unsigned short*)take((size_t)3 * FD * FD * 2);
    unsigned short* WcT   = (unsigned short*)take((size_t)CO * 3 * FD * 2);
    (void)ws_size; (void)n_in; (void)out_size;

    init_kernel <<<(n + 255) / 256, 256, 0, stream>>>(deg, fill, n);
    count_kernel<<<(e + 255) / 256, 256, 0, stream>>>(ei, deg, e);
    dis_kernel  <<<(n + 255) / 256, 256, 0, stream>>>(deg, dis, n);
    scan_kernel <<<1, 1024, 0, stream>>>(deg, rowptr, n);
    fill_kernel <<<(ep + 255) / 256, 256, 0, stream>>>(ei, dis, rowptr, fill, col, wv, e, n);

    const int total4 = n * FD / 4;
    conv_kernel  <<<(total4 + 255) / 256, 256, 0, stream>>>(x, xb, total4);
    wtrans_kernel<<<60, 256, 0, stream>>>(W0, W1, W2, Wc, WkT, WcT);

    spmm_bf16<<<(n + 3) / 4, 256, 0, stream>>>(rowptr, col, wv, xb, agg1b, n);
    spmm_bf16<<<(n + 3) / 4, 256, 0, stream>>>(rowptr, col, wv, agg1b, agg2b, n);

    fused_mfma<<<(n + 63) / 64, 256, 0, stream>>>(xb, agg1b, agg2b, WkT, b0, b1, b2,
                                                  WcT, bc, out, n);
}

// Round 3
// 239.076 us; speedup vs baseline: 3.1332x; 1.5993x over previous
//
#include <hip/hip_runtime.h>

// H2GCN: CSR build -> bf16 SpMM x2 (unroll-4) -> fused MFMA GEMM, m97-style
// pipelined staging: global_load_lds(16B) for in-tile + double-buffered W
// k-slices, counted vmcnt, raw s_barrier, XOR-swizzled LDS (pre-swizzled src).

#define FD 256   // D == H == 256
#define CO 64    // out channels
#define SB 512   // scan block

using frag_ab = __attribute__((ext_vector_type(8))) short;  // 8 bf16
using f32x4   = __attribute__((ext_vector_type(4))) float;
typedef unsigned short u16;
typedef unsigned int   u32;

__device__ __forceinline__ u16 f2bf(float f) {
    u32 u = __builtin_bit_cast(u32, f);
    return (u16)((u + 0x7FFFu + ((u >> 16) & 1u)) >> 16);
}
__device__ __forceinline__ float bf2f(u16 u) {
    u32 v = ((u32)u) << 16;
    return __builtin_bit_cast(float, v);
}

__device__ __forceinline__ void gll16(const void* g, void* l) {
    __builtin_amdgcn_global_load_lds(
        (const __attribute__((address_space(1))) u32*)g,
        (__attribute__((address_space(3))) u32*)l, 16, 0, 0);
}

#define BAR()  __builtin_amdgcn_s_barrier()
#define WLG0() asm volatile("s_waitcnt lgkmcnt(0)" ::: "memory")
#define WVM0() asm volatile("s_waitcnt vmcnt(0)" ::: "memory")
#define WVM4() asm volatile("s_waitcnt vmcnt(4)" ::: "memory")

// ---------------- CSR build ----------------
__global__ void init_kernel(int* deg, int* fill, int n) {
    int i = blockIdx.x * blockDim.x + threadIdx.x;
    if (i < n) { deg[i] = 1; fill[i] = 0; }
}
__global__ void count_kernel(const int* __restrict__ ei0, int* deg, int e) {
    int i = blockIdx.x * blockDim.x + threadIdx.x;
    if (i < e) atomicAdd(&deg[ei0[i]], 1);
}
__global__ void dis_kernel(const int* __restrict__ deg, float* __restrict__ dis, int n) {
    int i = blockIdx.x * blockDim.x + threadIdx.x;
    if (i < n) dis[i] = rsqrtf((float)deg[i]);
}
__global__ void scan1(const int* __restrict__ deg, int* __restrict__ rowptr,
                      int* __restrict__ bsum, int n) {
    __shared__ int sh[SB];
    int tid = threadIdx.x;
    int i = blockIdx.x * SB + tid;
    int v = (i < n) ? deg[i] : 0;
    sh[tid] = v;
    __syncthreads();
    for (int off = 1; off < SB; off <<= 1) {
        int add = (tid >= off) ? sh[tid - off] : 0;
        __syncthreads();
        sh[tid] += add;
        __syncthreads();
    }
    if (i < n) rowptr[i] = sh[tid] - v;
    if (tid == SB - 1) bsum[blockIdx.x] = sh[tid];
}
__global__ void scan2(const int* __restrict__ bsum, int* __restrict__ bscan, int nb) {
    __shared__ int sh[128];
    int tid = threadIdx.x;
    int v = (tid < nb) ? bsum[tid] : 0;
    sh[tid] = v;
    __syncthreads();
    for (int off = 1; off < 128; off <<= 1) {
        int add = (tid >= off) ? sh[tid - off] : 0;
        __syncthreads();
        sh[tid] += add;
        __syncthreads();
    }
    if (tid < nb) bscan[tid] = sh[tid] - v;
    if (tid == nb - 1) bscan[nb] = sh[tid];
}
__global__ void scan3(int* rowptr, const int* __restrict__ bscan, int n, int nb) {
    int i = blockIdx.x * 256 + threadIdx.x;
    if (i < n) rowptr[i] += bscan[i / SB];
    if (i == n) rowptr[n] = bscan[nb];
}
__global__ void fill_kernel(const int* __restrict__ ei, const float* __restrict__ dis,
                            const int* __restrict__ rowptr, int* fill,
                            int* __restrict__ col, float* __restrict__ wv, int e, int n) {
    int i = blockIdx.x * blockDim.x + threadIdx.x;
    if (i >= e + n) return;
    int r, c;
    if (i < e) { r = ei[i]; c = ei[e + i]; }
    else       { r = i - e; c = r; }
    float w = dis[r] * dis[c];
    int pos = rowptr[r] + atomicAdd(&fill[r], 1);
    col[pos] = c;
    wv[pos]  = w;
}

// ---------------- dtype prep ----------------
__global__ void conv_kernel(const float* __restrict__ x, u16* __restrict__ xb, int total4) {
    int i = blockIdx.x * blockDim.x + threadIdx.x;
    if (i < total4) {
        float4 v = ((const float4*)x)[i];
        ushort4 o;
        o.x = f2bf(v.x); o.y = f2bf(v.y); o.z = f2bf(v.z); o.w = f2bf(v.w);
        ((ushort4*)xb)[i] = o;
    }
}
__global__ void wtrans_kernel(const float* __restrict__ W0, const float* __restrict__ W1,
                              const float* __restrict__ W2, const float* __restrict__ Wc,
                              u16* __restrict__ WkT, u16* __restrict__ WcT) {
    __shared__ u16 tl[64][65];
    int b = blockIdx.x;
    const float* src; u16* dst; int R, C, r0, c0;
    if (b < 48) {
        int k = b >> 4, t = b & 15;
        src = (k == 0) ? W0 : (k == 1) ? W1 : W2;
        dst = WkT + k * 65536;
        R = 256; C = 256; r0 = (t >> 2) * 64; c0 = (t & 3) * 64;
    } else {
        int t = b - 48;
        src = Wc; dst = WcT;
        R = 768; C = 64; r0 = t * 64; c0 = 0;
    }
    int tid = threadIdx.x;
    int rr = tid >> 4, cc = (tid & 15) * 4;
    #pragma unroll
    for (int it = 0; it < 4; ++it) {
        int r = it * 16 + rr;
        float4 v = *(const float4*)(src + (size_t)(r0 + r) * C + c0 + cc);
        tl[cc + 0][r] = f2bf(v.x); tl[cc + 1][r] = f2bf(v.y);
        tl[cc + 2][r] = f2bf(v.z); tl[cc + 3][r] = f2bf(v.w);
    }
    __syncthreads();
    #pragma unroll
    for (int it = 0; it < 4; ++it) {
        int crow = it * 16 + rr;
        ushort4 o;
        o.x = tl[crow][cc + 0]; o.y = tl[crow][cc + 1];
        o.z = tl[crow][cc + 2]; o.w = tl[crow][cc + 3];
        *(ushort4*)(dst + (size_t)(c0 + crow) * R + r0 + cc) = o;
    }
}

// ---------------- SpMM (unroll-4, 4 gathers in flight) ----------------
__global__ void spmm_bf16(const int* __restrict__ rowptr, const int* __restrict__ col,
                          const float* __restrict__ wv, const u16* __restrict__ xb,
                          u16* __restrict__ outb, int n) {
    int row = blockIdx.x * 4 + (threadIdx.x >> 6);
    if (row >= n) return;
    int lane = threadIdx.x & 63;
    int p0 = rowptr[row], p1 = rowptr[row + 1];
    float a0 = 0.f, a1 = 0.f, a2 = 0.f, a3 = 0.f;
    int p = p0;
    for (; p + 4 <= p1; p += 4) {
        int c0 = col[p], c1 = col[p + 1], c2 = col[p + 2], c3 = col[p + 3];
        float w0 = wv[p], w1 = wv[p + 1], w2 = wv[p + 2], w3 = wv[p + 3];
        ushort4 v0 = *(const ushort4*)(xb + (size_t)c0 * FD + lane * 4);
        ushort4 v1 = *(const ushort4*)(xb + (size_t)c1 * FD + lane * 4);
        ushort4 v2 = *(const ushort4*)(xb + (size_t)c2 * FD + lane * 4);
        ushort4 v3 = *(const ushort4*)(xb + (size_t)c3 * FD + lane * 4);
        a0 += w0 * bf2f(v0.x) + w1 * bf2f(v1.x) + w2 * bf2f(v2.x) + w3 * bf2f(v3.x);
        a1 += w0 * bf2f(v0.y) + w1 * bf2f(v1.y) + w2 * bf2f(v2.y) + w3 * bf2f(v3.y);
        a2 += w0 * bf2f(v0.z) + w1 * bf2f(v1.z) + w2 * bf2f(v2.z) + w3 * bf2f(v3.z);
        a3 += w0 * bf2f(v0.w) + w1 * bf2f(v1.w) + w2 * bf2f(v2.w) + w3 * bf2f(v3.w);
    }
    for (; p < p1; ++p) {
        int c = col[p];
        float wt = wv[p];
        ushort4 v = *(const ushort4*)(xb + (size_t)c * FD + lane * 4);
        a0 += wt * bf2f(v.x); a1 += wt * bf2f(v.y);
        a2 += wt * bf2f(v.z); a3 += wt * bf2f(v.w);
    }
    ushort4 o;
    o.x = f2bf(a0); o.y = f2bf(a1); o.z = f2bf(a2); o.w = f2bf(a3);
    *(ushort4*)(outb + (size_t)row * FD + lane * 4) = o;
}

// ---------------- fused MFMA GEMM ----------------
// LDS map (64 KB):
//   inT  [0, 32768): in[64 r][256 k] bf16, byte(r,k16)=r*512+((k16^(r&7))<<4)
//                    (also reused for t[64 r][256 j] with same swizzle)
//   wb0  [32768, 49152), wb1 [49152, 65536): W[256 j][32 k] bf16,
//                    byte(j,k16)=j*64+((k16^((j>>1)&3))<<4)
__device__ __forceinline__ void issueW(const u16* WT, int kkw, char* dst, int w, int l) {
    #pragma unroll
    for (int c = 0; c < 4; ++c) {
        int Lw = w * 4096 + c * 1024 + l * 16;
        int j  = Lw >> 6;
        int s  = (Lw >> 4) & 3;
        int k16 = s ^ ((j >> 1) & 3);
        gll16(WT + (size_t)j * FD + kkw * 32 + k16 * 8, dst + w * 4096 + c * 1024);
    }
}

__launch_bounds__(256, 2)
__global__ void fused_mfma(const u16* __restrict__ xb, const u16* __restrict__ agg1b,
                           const u16* __restrict__ agg2b, const u16* __restrict__ WkT,
                           const float* __restrict__ b0, const float* __restrict__ b1,
                           const float* __restrict__ b2, const u16* __restrict__ WcT,
                           const float* __restrict__ bc, float* __restrict__ out, int n) {
    __shared__ __align__(16) char lds[65536];
    const int tid = threadIdx.x;
    const int w = tid >> 6, l = tid & 63;
    const int l4 = l >> 4, lm = l & 15;
    const int row0 = blockIdx.x * 64;

    char* inT = lds;
    char* wbuf0 = lds + 32768;
    char* wbuf1 = lds + 49152;

    f32x4 oacc[4];
    #pragma unroll
    for (int am = 0; am < 4; ++am) oacc[am] = (f32x4)(0.f);

    for (int k = 0; k < 3; ++k) {
        const u16* inb = (k == 0) ? xb : (k == 1) ? agg1b : agg2b;
        const u16* WT  = WkT + (size_t)k * 65536;
        const float* bk = (k == 0) ? b0 : (k == 1) ? b1 : b2;

        if (k == 0) {                       // hop>0: W(0),W(1) issued pre-stage-C
            issueW(WT, 0, wbuf0, w, l);
            issueW(WT, 1, wbuf1, w, l);
        }
        // in-tile staging (inT free: fresh at k=0, post-stage-C barrier at k>0)
        #pragma unroll
        for (int c = 0; c < 8; ++c) {
            int Lb = w * 8192 + c * 1024 + l * 16;
            int r  = Lb >> 9;
            int s  = (Lb >> 4) & 31;
            int k16 = s ^ (r & 7);
            int gr = row0 + r; if (gr > n - 1) gr = n - 1;
            gll16(inb + (size_t)gr * FD + k16 * 8, inT + w * 8192 + c * 1024);
        }
        WVM0();                              // in-tile + any W leftovers resident
        BAR();

        // ---- stage B: t^T = WT @ in^T, double-buffered W slices ----
        f32x4 acc[4][4];
        #pragma unroll
        for (int jm = 0; jm < 4; ++jm)
            #pragma unroll
            for (int rn = 0; rn < 4; ++rn) acc[jm][rn] = (f32x4)(0.f);

        #pragma unroll
        for (int kk = 0; kk < 8; ++kk) {
            char* wcur = (kk & 1) ? wbuf1 : wbuf0;
            frag_ab a[4], bfr[4];
            #pragma unroll
            for (int jm = 0; jm < 4; ++jm) {
                int j = w * 64 + jm * 16 + lm;
                a[jm] = *(const frag_ab*)(wcur + j * 64 + ((l4 ^ ((j >> 1) & 3)) << 4));
            }
            #pragma unroll
            for (int rn = 0; rn < 4; ++rn) {
                int r = rn * 16 + lm;
                bfr[rn] = *(const frag_ab*)(inT + r * 512 + (((kk * 4 + l4) ^ (r & 7)) << 4));
            }
            #pragma unroll
            for (int jm = 0; jm < 4; ++jm)
                #pragma unroll
                for (int rn = 0; rn < 4; ++rn)
                    acc[jm][rn] = __builtin_amdgcn_mfma_f32_16x16x32_bf16(a[jm], bfr[rn], acc[jm][rn], 0, 0, 0);

            WLG0();                          // my reads of wcur/inT complete
            BAR();                           // all waves done with W(kk)
            if (kk <= 5) {
                issueW(WT, kk + 2, (kk & 1) ? wbuf1 : wbuf0, w, l);
                WVM4();                      // W(kk+1) (older 4 issues) resident
            } else if (kk == 6) {
                WVM0();                      // W(7) resident
            }
            if (kk < 7) BAR();
        }

        // ---- bias + relu + pack t into inT (all stage-B reads done) ----
        #pragma unroll
        for (int jm = 0; jm < 4; ++jm) {
            float4 bb = *(const float4*)(bk + w * 64 + jm * 16 + l4 * 4);
            #pragma unroll
            for (int rn = 0; rn < 4; ++rn) {
                f32x4 v = acc[jm][rn];
                ushort4 p;
                p.x = f2bf(fmaxf(v[0] + bb.x, 0.f));
                p.y = f2bf(fmaxf(v[1] + bb.y, 0.f));
                p.z = f2bf(fmaxf(v[2] + bb.z, 0.f));
                p.w = f2bf(fmaxf(v[3] + bb.w, 0.f));
                int r = rn * 16 + lm;
                int j = w * 64 + jm * 16 + l4 * 4;
                *(ushort4*)(inT + r * 512 + (((j >> 3) ^ (r & 7)) << 4) + (j & 7) * 2) = p;
            }
        }
        WLG0();                              // pack writes complete
        BAR();

        if (k < 2) {                         // prefetch next hop's W(0),W(1)
            const u16* WTn = WkT + (size_t)(k + 1) * 65536;
            issueW(WTn, 0, wbuf0, w, l);
            issueW(WTn, 1, wbuf1, w, l);
        }

        // ---- stage C: out^T += WcT_k @ t^T ----
        const int rr = w * 16 + lm;
        #pragma unroll
        for (int kk = 0; kk < 8; ++kk) {
            frag_ab bfr = *(const frag_ab*)(inT + rr * 512 + (((kk * 4 + l4) ^ (rr & 7)) << 4));
            #pragma unroll
            for (int am = 0; am < 4; ++am) {
                frag_ab afr = *(const frag_ab*)(WcT + (size_t)(am * 16 + lm) * 768 + k * 256 + kk * 32 + 8 * l4);
                oacc[am] = __builtin_amdgcn_mfma_f32_16x16x32_bf16(afr, bfr, oacc[am], 0, 0, 0);
            }
        }
        WLG0();                              // t reads done before next hop staging
        BAR();
    }

    int gr = row0 + w * 16 + lm;
    if (gr < n) {
        #pragma unroll
        for (int am = 0; am < 4; ++am) {
            float4 bb = *(const float4*)(bc + am * 16 + l4 * 4);
            float4 o;
            o.x = oacc[am][0] + bb.x;
            o.y = oacc[am][1] + bb.y;
            o.z = oacc[am][2] + bb.z;
            o.w = oacc[am][3] + bb.w;
            *(float4*)(out + (size_t)gr * CO + am * 16 + l4 * 4) = o;
        }
    }
}

extern "C" void kernel_launch(void* const* d_in, const int* in_sizes, int n_in,
                              void* d_out, int out_size, void* d_ws, size_t ws_size,
                              hipStream_t stream) {
    const float* x  = (const float*)d_in[0];
    const int*   ei = (const int*)d_in[1];
    const float* W0 = (const float*)d_in[3];
    const float* b0 = (const float*)d_in[4];
    const float* W1 = (const float*)d_in[5];
    const float* b1 = (const float*)d_in[6];
    const float* W2 = (const float*)d_in[7];
    const float* b2 = (const float*)d_in[8];
    const float* Wc = (const float*)d_in[9];
    const float* bc = (const float*)d_in[10];
    float* out = (float*)d_out;

    const int n  = in_sizes[0] / FD;   // 50000
    const int e  = in_sizes[1] / 2;    // 400000
    const int ep = e + n;
    const int nb = (n + SB - 1) / SB;  // scan blocks

    char* ws = (char*)d_ws;
    size_t o = 0;
    auto take = [&](size_t nbytes) -> char* {
        char* p = ws + o;
        o += (nbytes + 255) & ~(size_t)255;
        return p;
    };
    int*   deg    = (int*)  take((size_t)n * 4);
    int*   fill   = (int*)  take((size_t)n * 4);
    float* dis    = (float*)take((size_t)n * 4);
    int*   rowptr = (int*)  take((size_t)(n + 1) * 4);
    int*   bsum   = (int*)  take((size_t)(nb + 1) * 4);
    int*   bscan  = (int*)  take((size_t)(nb + 1) * 4);
    int*   col    = (int*)  take((size_t)ep * 4);
    float* wv     = (float*)take((size_t)ep * 4);
    u16*   xb     = (u16*)  take((size_t)n * FD * 2);
    u16*   agg1b  = (u16*)  take((size_t)n * FD * 2);
    u16*   agg2b  = (u16*)  take((size_t)n * FD * 2);
    u16*   WkT    = (u16*)  take((size_t)3 * FD * FD * 2);
    u16*   WcT    = (u16*)  take((size_t)CO * 3 * FD * 2);
    (void)ws_size; (void)n_in; (void)out_size;

    init_kernel <<<(n + 255) / 256, 256, 0, stream>>>(deg, fill, n);
    count_kernel<<<(e + 255) / 256, 256, 0, stream>>>(ei, deg, e);
    dis_kernel  <<<(n + 255) / 256, 256, 0, stream>>>(deg, dis, n);
    scan1       <<<nb, SB, 0, stream>>>(deg, rowptr, bsum, n);
    scan2       <<<1, 128, 0, stream>>>(bsum, bscan, nb);
    scan3       <<<(n + 256) / 256, 256, 0, stream>>>(rowptr, bscan, n, nb);
    fill_kernel <<<(ep + 255) / 256, 256, 0, stream>>>(ei, dis, rowptr, fill, col, wv, e, n);

    const int total4 = n * FD / 4;
    conv_kernel  <<<(total4 + 255) / 256, 256, 0, stream>>>(x, xb, total4);
    wtrans_kernel<<<60, 256, 0, stream>>>(W0, W1, W2, Wc, WkT, WcT);

    spmm_bf16<<<(n + 3) / 4, 256, 0, stream>>>(rowptr, col, wv, xb, agg1b, n);
    spmm_bf16<<<(n + 3) / 4, 256, 0, stream>>>(rowptr, col, wv, agg1b, agg2b, n);

    fused_mfma<<<(n + 63) / 64, 256, 0, stream>>>(xb, agg1b, agg2b, WkT, b0, b1, b2,
                                                  WcT, bc, out, n);
}